// Round 6
// baseline (218.415 us; speedup 1.0000x reference)
//
#include <hip/hip_runtime.h>
#include <hip/hip_bf16.h>
#include <math.h>

#define B_   4
#define C_   256
#define H_   96
#define W_   96
#define HW_  (H_ * W_)
#define G_   4
#define CG_  64
#define K_   9
#define PW_  98                            // padded width/height (1-px halo)
#define PROW_ (PW_ * C_)                   // padded row pitch in elems

typedef __bf16  bf16x8 __attribute__((ext_vector_type(8)));
typedef float   f32x4  __attribute__((ext_vector_type(4)));

// ---------------------------------------------------------------------------
// prep:
//  aOW: offset-conv weights, MFMA A order, M padded 18->32:
//    m = mt*16 + (lane&15) (out chan, 0 if >=18); k = ks*32+(lane>>4)*8+j (c)
//  aW: deform weights bf16, MFMA A order:
//    c = ks*32+(lane>>4)*8+j ; co = cq*16+(lane&15)  (cq = half*2+ct)
// ---------------------------------------------------------------------------
__global__ __launch_bounds__(256) void prep_kernel(
    const float* __restrict__ ow, const float* __restrict__ wt,
    __hip_bfloat16* __restrict__ aOW, __hip_bfloat16* __restrict__ aW)
{
    int idx = blockIdx.x * 256 + threadIdx.x;
    if (idx < 73728) {
        int j    = idx & 7;
        int r    = idx >> 3;
        int lane = r & 63;  r >>= 6;
        int mt   = r & 1;   r >>= 1;
        int ks   = r & 7;   r >>= 3;
        int tap  = r;                     // 0..8
        int m = mt * 16 + (lane & 15);
        int c = ks * 32 + (lane >> 4) * 8 + j;
        float v = (m < 18) ? ow[(m * 256 + c) * 9 + tap] : 0.f;
        aOW[idx] = __float2bfloat16(v);
    }
    if (idx < 147456) {
        int j    = idx & 7;
        int r    = idx >> 3;
        int lane = r & 63;  r >>= 6;
        int cq   = r & 3;   r >>= 2;
        int ks   = r & 1;   r >>= 1;
        int tap  = r % 9;
        int g    = r / 9;
        int c  = ks * 32 + (lane >> 4) * 8 + j;
        int co = cq * 16 + (lane & 15);
        float v = wt[(((g * CG_ + co) * CG_ + c) * 9) + tap];
        aW[idx] = __float2bfloat16(v);
    }
}

// ---------------------------------------------------------------------------
// transpose x (NCHW fp32) -> xtp (padded NHWC bf16, [b][98][98][256], halo=0).
// ---------------------------------------------------------------------------
__global__ __launch_bounds__(256) void transpose_kernel(
    const float* __restrict__ x, __hip_bfloat16* __restrict__ xtp)
{
    int blk = blockIdx.x;                 // 0..383 = b*96 + h
    int b = blk / H_, h = blk - b * H_;
    int t = threadIdx.x;
    __shared__ __align__(16) __hip_bfloat16 tile[96 * 264];
    const float* xb = x + (size_t)b * C_ * HW_ + h * W_;
    for (int r = 0; r < 96; ++r) {
        int e = r * 256 + t;              // 0..24575
        int c = e / 96, w = e - c * 96;
        tile[w * 264 + c] = __float2bfloat16(xb[c * HW_ + w]);
    }
    __syncthreads();
    __hip_bfloat16* ob = xtp + ((size_t)(b * PW_ + h + 1) * PW_ + 1) * C_;
#pragma unroll
    for (int i = 0; i < 12; ++i) {
        int sIdx = i * 256 + t;           // 0..3071
        int px = sIdx >> 5, seg = sIdx & 31;
        *(bf16x8*)(ob + px * 256 + seg * 8) =
            *(const bf16x8*)(&tile[px * 264 + seg * 8]);
    }
    bf16x8 z = {};
    if (t < 64) {                         // column halos of this row
        int side = t >> 5, i = t & 31;
        *(bf16x8*)(xtp + ((size_t)(b * PW_ + h + 1) * PW_ + side * 97) * C_ + i * 8) = z;
    }
    if (h == 0 || h == 95) {              // top/bottom halo rows
        int row = (h == 0) ? 0 : 97;
        __hip_bfloat16* rb = xtp + (size_t)(b * PW_ + row) * PROW_;
#pragma unroll
        for (int i = 0; i < 13; ++i) {
            int idx = i * 256 + t;
            if (idx < 3136) *(bf16x8*)(rb + idx * 8) = z;
        }
    }
}

// ---------------------------------------------------------------------------
// offset conv via MFMA (unchanged from r5).
// ---------------------------------------------------------------------------
__global__ __launch_bounds__(384) void offset_conv_kernel(
    const __hip_bfloat16* __restrict__ xtp, const __hip_bfloat16* __restrict__ aOW,
    const float* __restrict__ bias, __hip_bfloat16* __restrict__ off2)
{
    int blk = blockIdx.x;                 // 0..383
    int xcd = blk & 7;
    int s   = blk >> 3;                   // 0..47
    int bh  = xcd * 48 + s;               // XCD-chunked: neighbors share rows
    int b   = bh / H_, h = bh % H_;
    int t = threadIdx.x, lane = t & 63;
    int nt = __builtin_amdgcn_readfirstlane(t >> 6);  // 0..5 -> w tile
    int w0 = nt * 16;
    int ml = lane & 15, kq = lane >> 4;

    f32x4 acc0 = {}, acc1 = {};
    const __hip_bfloat16* xb = xtp + (size_t)b * (PW_ * PROW_);
#pragma unroll
    for (int ky = 0; ky < 3; ++ky) {
#pragma unroll
        for (int kx = 0; kx < 3; ++kx) {
            int tap = ky * 3 + kx;
            const __hip_bfloat16* brow =
                xb + ((h + ky) * PW_ + (w0 + ml + kx)) * C_ + kq * 8;
            const __hip_bfloat16* arow = aOW + tap * 8192 + lane * 8;
#pragma unroll
            for (int ks = 0; ks < 8; ++ks) {
                bf16x8 bf = *(const bf16x8*)(brow + ks * 32);
                bf16x8 a0 = *(const bf16x8*)(arow + ks * 1024);
                bf16x8 a1 = *(const bf16x8*)(arow + ks * 1024 + 512);
                acc0 = __builtin_amdgcn_mfma_f32_16x16x32_bf16(a0, bf, acc0, 0, 0, 0);
                acc1 = __builtin_amdgcn_mfma_f32_16x16x32_bf16(a1, bf, acc1, 0, 0, 0);
            }
        }
    }
    // C/D: col=lane&15 -> w, row=kq*4+r -> out channel j
    int w = w0 + ml;
#pragma unroll
    for (int r = 0; r < 4; ++r) {
        int j0 = kq * 4 + r;
        off2[((size_t)(b * 9 + (j0 >> 1)) * HW_ + h * W_ + w) * 2 + (j0 & 1)] =
            __float2bfloat16(acc0[r] + bias[j0]);
        int j1 = 16 + kq * 4 + r;
        if (j1 < 18)
            off2[((size_t)(b * 9 + (j1 >> 1)) * HW_ + h * W_ + w) * 2 + (j1 & 1)] =
                __float2bfloat16(acc1[r] + bias[j1]);
    }
}

// ---------------------------------------------------------------------------
// deform conv via MFMA, register-direct sampling (no LDS, no barriers).
// Block = (b,g,h), 192 thr = 3 waves; wave tile = 64co x 32w (wthird).
// Lane (n=lane&15, kq=lane>>4) samples B-frags itself: for wt in {0,1},
// w = wthird*32+wt*16+n; for ks in {0,1}, c = ks*32+kq*8..+8 -> one bf16x8
// frag per (wt,ks), exactly the 16x16x32 B lane layout. 16 MFMAs/tap/wave.
// Waves run free (TLP hides vmcnt stalls); 12 waves/CU via lb(192,3).
// ---------------------------------------------------------------------------
__global__ __launch_bounds__(192, 3) void deform_kernel(
    const __hip_bfloat16* __restrict__ xtp, const __hip_bfloat16* __restrict__ off2,
    const __hip_bfloat16* __restrict__ aW, float* __restrict__ out)
{
    int blk = blockIdx.x;                 // 0..1535
    int xcd = blk & 7;
    int s   = blk >> 3;                   // 0..191
    int bg  = xcd * 2 + (s / H_);         // 0..15
    int h   = s % H_;
    int g   = bg & 3;
    int b   = bg >> 2;
    int lane   = threadIdx.x & 63;
    int wthird = __builtin_amdgcn_readfirstlane(threadIdx.x >> 6); // 0..2
    int n  = lane & 15;
    int kq = lane >> 4;

    const __hip_bfloat16* xb =
        xtp + ((size_t)b * (PW_ * PW_) + 99) * C_ + g * CG_ + kq * 8;
    const __hip_bfloat162* offp =
        (const __hip_bfloat162*)off2 + (size_t)(b * 9) * HW_ + h * W_;
    const __hip_bfloat16* aWg = aW + (g * 9) * 4096 + lane * 8;

    f32x4 acc[4][2] = {};                 // [cq co16][wt w16]

    for (int k = 0; k < K_; ++k) {
        int ky = k / 3, kx = k - ky * 3;

        // A-frags for this tap (L2-resident; latency hidden under sampling)
        bf16x8 afrag[2][4];               // [ks][cq]
        const __hip_bfloat16* at = aWg + k * 4096;
#pragma unroll
        for (int ks = 0; ks < 2; ++ks)
#pragma unroll
            for (int cq = 0; cq < 4; ++cq)
                afrag[ks][cq] = *(const bf16x8*)(at + ks * 2048 + cq * 512);

        // sample own B-frags into registers
        bf16x8 bfrag[2][2];               // [wt][ks]
#pragma unroll
        for (int wt = 0; wt < 2; ++wt) {
            int w = wthird * 32 + wt * 16 + n;
            __hip_bfloat162 pr = offp[k * HW_ + w];
            float dy = __bfloat162float(pr.x);
            float dx = __bfloat162float(pr.y);
            float py = (float)(h + ky - 1) + dy;
            float px = (float)(w + kx - 1) + dx;
            bool valid = (py > -1.f) && (py < (float)H_) &&
                         (px > -1.f) && (px < (float)W_);
            float y0f = floorf(py), x0f = floorf(px);
            float ly = py - y0f, lx = px - x0f;
            int y0 = (int)y0f, x0 = (int)x0f;
            int y1 = y0 + 1,  x1 = x0 + 1;
            bool y0ok = valid && (y0 >= 0) && (y0 < H_);
            bool y1ok = valid && (y1 >= 0) && (y1 < H_);
            bool x0ok = (x0 >= 0) && (x0 < W_);
            bool x1ok = (x1 >= 0) && (x1 < W_);
            int y0c = min(max(y0, 0), H_ - 1);
            int y1c = min(max(y1, 0), H_ - 1);
            int x0c = min(max(x0, 0), W_ - 1);
            int x1c = min(max(x1, 0), W_ - 1);
            float bw00 = (y0ok && x0ok) ? (1.f - ly) * (1.f - lx) : 0.f;
            float bw01 = (y0ok && x1ok) ? (1.f - ly) * lx : 0.f;
            float bw10 = (y1ok && x0ok) ? ly * (1.f - lx) : 0.f;
            float bw11 = (y1ok && x1ok) ? ly * lx : 0.f;
            const __hip_bfloat16* p00 = xb + (y0c * PW_ + x0c) * C_;
            const __hip_bfloat16* p01 = xb + (y0c * PW_ + x1c) * C_;
            const __hip_bfloat16* p10 = xb + (y1c * PW_ + x0c) * C_;
            const __hip_bfloat16* p11 = xb + (y1c * PW_ + x1c) * C_;
#pragma unroll
            for (int ks = 0; ks < 2; ++ks) {
                bf16x8 c00 = *(const bf16x8*)(p00 + ks * 32);
                bf16x8 c01 = *(const bf16x8*)(p01 + ks * 32);
                bf16x8 c10 = *(const bf16x8*)(p10 + ks * 32);
                bf16x8 c11 = *(const bf16x8*)(p11 + ks * 32);
                bf16x8 r;
#pragma unroll
                for (int e = 0; e < 8; ++e) {
                    float v = bw00 * (float)c00[e] + bw01 * (float)c01[e]
                            + bw10 * (float)c10[e] + bw11 * (float)c11[e];
                    r[e] = (__bf16)v;
                }
                bfrag[wt][ks] = r;
            }
        }

        // 16 MFMAs: acc[cq][wt] += A[ks][cq] * B[wt][ks]
#pragma unroll
        for (int ks = 0; ks < 2; ++ks)
#pragma unroll
            for (int wt = 0; wt < 2; ++wt)
#pragma unroll
                for (int cq = 0; cq < 4; ++cq)
                    acc[cq][wt] = __builtin_amdgcn_mfma_f32_16x16x32_bf16(
                        afrag[ks][cq], bfrag[wt][ks], acc[cq][wt], 0, 0, 0);
    }

    // epilogue: C/D col=lane&15 -> w, row=kq*4+r -> co (within cq tile)
    float* ob = out + ((b * C_ + g * CG_) * HW_) + h * W_ + wthird * 32;
#pragma unroll
    for (int cq = 0; cq < 4; ++cq)
#pragma unroll
        for (int wt = 0; wt < 2; ++wt)
#pragma unroll
            for (int r = 0; r < 4; ++r)
                __builtin_nontemporal_store(
                    acc[cq][wt][r],
                    ob + (cq * 16 + kq * 4 + r) * HW_ + wt * 16 + n);
}

// ---------------------------------------------------------------------------
extern "C" void kernel_launch(void* const* d_in, const int* in_sizes, int n_in,
                              void* d_out, int out_size, void* d_ws, size_t ws_size,
                              hipStream_t stream) {
    const float* x    = (const float*)d_in[0];
    const float* ow   = (const float*)d_in[1];   // offset_w (18,256,3,3)
    const float* obi  = (const float*)d_in[2];   // offset_b (18,)
    const float* wt   = (const float*)d_in[3];   // weight   (256,64,3,3)

    // ws: xtp bf16 padded (19.67MB) | off2 bf16 (1.33MB) | aW (0.29MB) | aOW (0.15MB)
    __hip_bfloat16* xtp  = (__hip_bfloat16*)d_ws;
    __hip_bfloat16* off2 = xtp + (size_t)B_ * PW_ * PW_ * C_;
    __hip_bfloat16* aW   = off2 + (size_t)B_ * 9 * HW_ * 2;
    __hip_bfloat16* aOW  = aW + 147456;

    prep_kernel<<<576, 256, 0, stream>>>(ow, wt, aOW, aW);
    transpose_kernel<<<B_ * H_, 256, 0, stream>>>(x, xtp);
    offset_conv_kernel<<<B_ * H_, 384, 0, stream>>>(xtp, aOW, obi, off2);
    deform_kernel<<<B_ * G_ * H_, 192, 0, stream>>>(xtp, off2, aW, (float*)d_out);
}

// Round 7
// 200.015 us; speedup vs baseline: 1.0920x; 1.0920x over previous
//
#include <hip/hip_runtime.h>
#include <hip/hip_bf16.h>
#include <math.h>

#define B_   4
#define C_   256
#define H_   96
#define W_   96
#define HW_  (H_ * W_)
#define G_   4
#define CG_  64
#define K_   9
#define PW_  98                            // padded width/height (1-px halo)
#define PROW_ (PW_ * C_)                   // padded row pitch in elems

typedef __bf16  bf16x8 __attribute__((ext_vector_type(8)));
typedef float   f32x4  __attribute__((ext_vector_type(4)));

// ---------------------------------------------------------------------------
// prep:
//  aOW: offset-conv weights, MFMA A order, M padded 18->32:
//    m = mt*16 + (lane&15) (out chan, 0 if >=18); k = ks*32+(lane>>4)*8+j (c)
//  aW: deform weights bf16, MFMA A order:
//    c = ks*32+(lane>>4)*8+j ; co = half*32+ct*16+(lane&15)
// ---------------------------------------------------------------------------
__global__ __launch_bounds__(256) void prep_kernel(
    const float* __restrict__ ow, const float* __restrict__ wt,
    __hip_bfloat16* __restrict__ aOW, __hip_bfloat16* __restrict__ aW)
{
    int idx = blockIdx.x * 256 + threadIdx.x;
    if (idx < 73728) {
        int j    = idx & 7;
        int r    = idx >> 3;
        int lane = r & 63;  r >>= 6;
        int mt   = r & 1;   r >>= 1;
        int ks   = r & 7;   r >>= 3;
        int tap  = r;                     // 0..8
        int m = mt * 16 + (lane & 15);
        int c = ks * 32 + (lane >> 4) * 8 + j;
        float v = (m < 18) ? ow[(m * 256 + c) * 9 + tap] : 0.f;
        aOW[idx] = __float2bfloat16(v);
    }
    if (idx < 147456) {
        int j    = idx & 7;
        int r    = idx >> 3;
        int lane = r & 63;  r >>= 6;
        int ct   = r & 1;   r >>= 1;
        int half = r & 1;   r >>= 1;
        int ks   = r & 1;   r >>= 1;
        int tap  = r % 9;
        int g    = r / 9;
        int c  = ks * 32 + (lane >> 4) * 8 + j;
        int co = half * 32 + ct * 16 + (lane & 15);
        float v = wt[(((g * CG_ + co) * CG_ + c) * 9) + tap];
        aW[idx] = __float2bfloat16(v);
    }
}

// ---------------------------------------------------------------------------
// transpose x (NCHW fp32) -> xtp (padded NHWC bf16, [b][98][98][256], halo=0).
// ---------------------------------------------------------------------------
__global__ __launch_bounds__(256) void transpose_kernel(
    const float* __restrict__ x, __hip_bfloat16* __restrict__ xtp)
{
    int blk = blockIdx.x;                 // 0..383 = b*96 + h
    int b = blk / H_, h = blk - b * H_;
    int t = threadIdx.x;
    __shared__ __align__(16) __hip_bfloat16 tile[96 * 264];
    const float* xb = x + (size_t)b * C_ * HW_ + h * W_;
    for (int r = 0; r < 96; ++r) {
        int e = r * 256 + t;              // 0..24575
        int c = e / 96, w = e - c * 96;
        tile[w * 264 + c] = __float2bfloat16(xb[c * HW_ + w]);
    }
    __syncthreads();
    __hip_bfloat16* ob = xtp + ((size_t)(b * PW_ + h + 1) * PW_ + 1) * C_;
#pragma unroll
    for (int i = 0; i < 12; ++i) {
        int sIdx = i * 256 + t;           // 0..3071
        int px = sIdx >> 5, seg = sIdx & 31;
        *(bf16x8*)(ob + px * 256 + seg * 8) =
            *(const bf16x8*)(&tile[px * 264 + seg * 8]);
    }
    bf16x8 z = {};
    if (t < 64) {                         // column halos of this row
        int side = t >> 5, i = t & 31;
        *(bf16x8*)(xtp + ((size_t)(b * PW_ + h + 1) * PW_ + side * 97) * C_ + i * 8) = z;
    }
    if (h == 0 || h == 95) {              // top/bottom halo rows
        int row = (h == 0) ? 0 : 97;
        __hip_bfloat16* rb = xtp + (size_t)(b * PW_ + row) * PROW_;
#pragma unroll
        for (int i = 0; i < 13; ++i) {
            int idx = i * 256 + t;
            if (idx < 3136) *(bf16x8*)(rb + idx * 8) = z;
        }
    }
}

// ---------------------------------------------------------------------------
// offset conv via MFMA, K-split: 384 blocks x 768 thr = 12 waves =
// 6 w-tiles(16) x 2 k-halves (c 0..127 / 128..255). Each wave: M=32 x N=16 x
// K=1152 (9 taps x 4 ks). LDS reduce across the 2 halves at the end.
// 18 waves/CU (vs 9 in r5) for latency hiding; half-length MFMA chains.
// ---------------------------------------------------------------------------
__global__ __launch_bounds__(768) void offset_conv_kernel(
    const __hip_bfloat16* __restrict__ xtp, const __hip_bfloat16* __restrict__ aOW,
    const float* __restrict__ bias, __hip_bfloat16* __restrict__ off2)
{
    int blk = blockIdx.x;                 // 0..383
    int xcd = blk & 7;
    int s   = blk >> 3;                   // 0..47
    int bh  = xcd * 48 + s;               // XCD-chunked: neighbors share rows
    int b   = bh / H_, h = bh % H_;
    int t = threadIdx.x, lane = t & 63;
    int ww = __builtin_amdgcn_readfirstlane(t >> 6);  // 0..11
    int nt = ww % 6;                      // w tile
    int kh = ww / 6;                      // k half
    int w0 = nt * 16;
    int ml = lane & 15, kq = lane >> 4;

    f32x4 acc0 = {}, acc1 = {};
    const __hip_bfloat16* xb = xtp + (size_t)b * (PW_ * PROW_);
#pragma unroll
    for (int ky = 0; ky < 3; ++ky) {
#pragma unroll
        for (int kx = 0; kx < 3; ++kx) {
            int tap = ky * 3 + kx;
            const __hip_bfloat16* brow =
                xb + ((h + ky) * PW_ + (w0 + ml + kx)) * C_ + kh * 128 + kq * 8;
            const __hip_bfloat16* arow = aOW + tap * 8192 + kh * 4096 + lane * 8;
#pragma unroll
            for (int ks = 0; ks < 4; ++ks) {
                bf16x8 bf = *(const bf16x8*)(brow + ks * 32);
                bf16x8 a0 = *(const bf16x8*)(arow + ks * 1024);
                bf16x8 a1 = *(const bf16x8*)(arow + ks * 1024 + 512);
                acc0 = __builtin_amdgcn_mfma_f32_16x16x32_bf16(a0, bf, acc0, 0, 0, 0);
                acc1 = __builtin_amdgcn_mfma_f32_16x16x32_bf16(a1, bf, acc1, 0, 0, 0);
            }
        }
    }
    // cross-half reduction in LDS
    __shared__ __align__(16) f32x4 red[6 * 64 * 2];
    if (kh == 1) {
        red[(nt * 64 + lane) * 2 + 0] = acc0;
        red[(nt * 64 + lane) * 2 + 1] = acc1;
    }
    __syncthreads();
    if (kh == 0) {
        f32x4 r0 = red[(nt * 64 + lane) * 2 + 0];
        f32x4 r1 = red[(nt * 64 + lane) * 2 + 1];
        acc0 += r0;
        acc1 += r1;
        // C/D: col=lane&15 -> w, row=kq*4+r -> out channel j
        int w = w0 + ml;
#pragma unroll
        for (int r = 0; r < 4; ++r) {
            int j0 = kq * 4 + r;
            off2[((size_t)(b * 9 + (j0 >> 1)) * HW_ + h * W_ + w) * 2 + (j0 & 1)] =
                __float2bfloat16(acc0[r] + bias[j0]);
            int j1 = 16 + kq * 4 + r;
            if (j1 < 18)
                off2[((size_t)(b * 9 + (j1 >> 1)) * HW_ + h * W_ + w) * 2 + (j1 & 1)] =
                    __float2bfloat16(acc1[r] + bias[j1]);
        }
    }
}

// ---------------------------------------------------------------------------
// deform conv via MFMA (r5 structure: double-buffered LDS B-tile, 1 barrier
// per tap, sample(k+1) overlaps mmtap(k)) + NEW: per-(tap,w) bilinear setup
// deduped into an LDS table built once per block (was 8x redundant VALU).
// Block = (b,g,h), 384 thr = 6 waves.
// ---------------------------------------------------------------------------
__global__ __launch_bounds__(384, 4) void deform_kernel(
    const __hip_bfloat16* __restrict__ xtp, const __hip_bfloat16* __restrict__ off2,
    const __hip_bfloat16* __restrict__ aW, float* __restrict__ out)
{
    int blk = blockIdx.x;                 // 0..1535
    int xcd = blk & 7;
    int s   = blk >> 3;                   // 0..191
    int bg  = xcd * 2 + (s / H_);         // 0..15
    int h   = s % H_;
    int g   = bg & 3;
    int b   = bg >> 2;
    int t    = threadIdx.x;
    int lane = t & 63;
    int wave = __builtin_amdgcn_readfirstlane(t >> 6);  // 0..5
    int half   = wave & 1;                // co half (32)
    int wthird = wave >> 1;               // w third (32)

    __shared__ __align__(16) __hip_bfloat16 sS[2][96 * 72]; // [w][64c+pad]
    __shared__ __align__(16) f32x4 bwt[864];                // [tap][w] weights
    __shared__ __align__(16) int4  oft[864];                // [tap][w] offsets

    const __hip_bfloat16* xb = xtp + ((size_t)b * (PW_ * PW_) + 99) * C_ + g * CG_;
    const __hip_bfloat162* offp =
        (const __hip_bfloat162*)off2 + (size_t)(b * 9) * HW_ + h * W_;
    const __hip_bfloat16* aWg = aW + (g * 9) * 4096;

    int tw8 = t >> 3;                     // 0..47
    int j8  = (t & 7) * 8;                // c offset within group

    // ---- build bilinear tables for all 9 taps x 96 w (once per block) ----
    for (int e = t; e < 864; e += 384) {
        int k = e / 96, w = e - (e / 96) * 96;
        int ky = k / 3, kx = k - ky * 3;
        __hip_bfloat162 pr = offp[k * HW_ + w];
        float dy = __bfloat162float(pr.x);
        float dx = __bfloat162float(pr.y);
        float py = (float)(h + ky - 1) + dy;
        float px = (float)(w + kx - 1) + dx;
        bool valid = (py > -1.f) && (py < (float)H_) &&
                     (px > -1.f) && (px < (float)W_);
        float y0f = floorf(py), x0f = floorf(px);
        float ly = py - y0f, lx = px - x0f;
        int y0 = (int)y0f, x0 = (int)x0f;
        int y1 = y0 + 1,  x1 = x0 + 1;
        bool y0ok = valid && (y0 >= 0) && (y0 < H_);
        bool y1ok = valid && (y1 >= 0) && (y1 < H_);
        bool x0ok = (x0 >= 0) && (x0 < W_);
        bool x1ok = (x1 >= 0) && (x1 < W_);
        int y0c = min(max(y0, 0), H_ - 1);
        int y1c = min(max(y1, 0), H_ - 1);
        int x0c = min(max(x0, 0), W_ - 1);
        int x1c = min(max(x1, 0), W_ - 1);
        f32x4 bw;
        bw[0] = (y0ok && x0ok) ? (1.f - ly) * (1.f - lx) : 0.f;
        bw[1] = (y0ok && x1ok) ? (1.f - ly) * lx : 0.f;
        bw[2] = (y1ok && x0ok) ? ly * (1.f - lx) : 0.f;
        bw[3] = (y1ok && x1ok) ? ly * lx : 0.f;
        bwt[e] = bw;
        oft[e] = make_int4((y0c * PW_ + x0c) * C_,     // p00
                           (x1c - x0c) * C_,           // +dx
                           (y1c - y0c) * PROW_, 0);    // +dy
    }

    f32x4 acc[2][2] = {};                 // [ct co16][wt w16]

    auto sample = [&](int k, int p) {
#pragma unroll
        for (int it = 0; it < 2; ++it) {
            int w  = it * 48 + tw8;
            int e  = k * 96 + w;
            f32x4 bw = bwt[e];
            int4  of = oft[e];
            const __hip_bfloat16* p00 = xb + of.x;
            const __hip_bfloat16* p01 = xb + of.x + of.y;
            const __hip_bfloat16* p10 = xb + of.x + of.z;
            const __hip_bfloat16* p11 = xb + of.x + of.y + of.z;
            bf16x8 c00 = *(const bf16x8*)(p00 + j8);
            bf16x8 c01 = *(const bf16x8*)(p01 + j8);
            bf16x8 c10 = *(const bf16x8*)(p10 + j8);
            bf16x8 c11 = *(const bf16x8*)(p11 + j8);
            bf16x8 r;
#pragma unroll
            for (int e2 = 0; e2 < 8; ++e2) {
                float v = bw[0] * (float)c00[e2] + bw[1] * (float)c01[e2]
                        + bw[2] * (float)c10[e2] + bw[3] * (float)c11[e2];
                r[e2] = (__bf16)v;
            }
            *(bf16x8*)(&sS[p][w * 72 + j8]) = r;
        }
    };

    auto mmtap = [&](int k, int p) {
        bf16x8 afrag[2][2];               // [ks][ct]
        const __hip_bfloat16* at = aWg + k * 4096 + half * 1024 + lane * 8;
#pragma unroll
        for (int ks = 0; ks < 2; ++ks)
#pragma unroll
            for (int ct = 0; ct < 2; ++ct)
                afrag[ks][ct] = *(const bf16x8*)(at + ks * 2048 + ct * 512);
#pragma unroll
        for (int ks = 0; ks < 2; ++ks) {
#pragma unroll
            for (int wt = 0; wt < 2; ++wt) {
                int wrow = wthird * 32 + wt * 16 + (lane & 15);
                bf16x8 bfrag = *(const bf16x8*)(
                    &sS[p][wrow * 72 + ks * 32 + (lane >> 4) * 8]);
                acc[0][wt] = __builtin_amdgcn_mfma_f32_16x16x32_bf16(
                                 afrag[ks][0], bfrag, acc[0][wt], 0, 0, 0);
                acc[1][wt] = __builtin_amdgcn_mfma_f32_16x16x32_bf16(
                                 afrag[ks][1], bfrag, acc[1][wt], 0, 0, 0);
            }
        }
    };

    __syncthreads();                      // tables ready
    sample(0, 0);
    __syncthreads();
    for (int k = 0; k < K_; ++k) {
        if (k < K_ - 1) sample(k + 1, (k + 1) & 1);  // loads issue early
        mmtap(k, k & 1);
        __syncthreads();
    }

    // epilogue: C/D layout col=lane&15 (w), row=(lane>>4)*4+reg (co)
    float* ob = out + ((b * C_ + g * CG_ + half * 32) * HW_) + h * W_ + wthird * 32;
    int rbase = (lane >> 4) * 4;
    int ncol  = lane & 15;
#pragma unroll
    for (int ct = 0; ct < 2; ++ct)
#pragma unroll
        for (int wt = 0; wt < 2; ++wt)
#pragma unroll
            for (int r = 0; r < 4; ++r)
                __builtin_nontemporal_store(
                    acc[ct][wt][r],
                    ob + (ct * 16 + rbase + r) * HW_ + wt * 16 + ncol);
}

// ---------------------------------------------------------------------------
extern "C" void kernel_launch(void* const* d_in, const int* in_sizes, int n_in,
                              void* d_out, int out_size, void* d_ws, size_t ws_size,
                              hipStream_t stream) {
    const float* x    = (const float*)d_in[0];
    const float* ow   = (const float*)d_in[1];   // offset_w (18,256,3,3)
    const float* obi  = (const float*)d_in[2];   // offset_b (18,)
    const float* wt   = (const float*)d_in[3];   // weight   (256,64,3,3)

    // ws: xtp bf16 padded (19.67MB) | off2 bf16 (1.33MB) | aW (0.29MB) | aOW (0.15MB)
    __hip_bfloat16* xtp  = (__hip_bfloat16*)d_ws;
    __hip_bfloat16* off2 = xtp + (size_t)B_ * PW_ * PW_ * C_;
    __hip_bfloat16* aW   = off2 + (size_t)B_ * 9 * HW_ * 2;
    __hip_bfloat16* aOW  = aW + 147456;

    prep_kernel<<<576, 256, 0, stream>>>(ow, wt, aOW, aW);
    transpose_kernel<<<B_ * H_, 256, 0, stream>>>(x, xtp);
    offset_conv_kernel<<<B_ * H_, 768, 0, stream>>>(xtp, aOW, obi, off2);
    deform_kernel<<<B_ * G_ * H_, 384, 0, stream>>>(xtp, off2, aW, (float*)d_out);
}

// Round 8
// 177.379 us; speedup vs baseline: 1.2313x; 1.1276x over previous
//
#include <hip/hip_runtime.h>
#include <hip/hip_bf16.h>
#include <math.h>

#define B_   4
#define C_   256
#define H_   96
#define W_   96
#define HW_  (H_ * W_)
#define G_   4
#define CG_  64
#define K_   9
#define PW_  98                            // padded width/height (1-px halo)
#define PROW_ (PW_ * C_)                   // padded row pitch in elems

typedef __bf16  bf16x8 __attribute__((ext_vector_type(8)));
typedef float   f32x4  __attribute__((ext_vector_type(4)));

// ---------------------------------------------------------------------------
// prep:
//  aOW: offset-conv weights, MFMA A order, M padded 18->32:
//    m = mt*16 + (lane&15) (out chan, 0 if >=18); k = ks*32+(lane>>4)*8+j (c)
//  aW: deform weights bf16, MFMA A order:
//    c = ks*32+(lane>>4)*8+j ; co = half*32+ct*16+(lane&15)
// ---------------------------------------------------------------------------
__global__ __launch_bounds__(256) void prep_kernel(
    const float* __restrict__ ow, const float* __restrict__ wt,
    __hip_bfloat16* __restrict__ aOW, __hip_bfloat16* __restrict__ aW)
{
    int idx = blockIdx.x * 256 + threadIdx.x;
    if (idx < 73728) {
        int j    = idx & 7;
        int r    = idx >> 3;
        int lane = r & 63;  r >>= 6;
        int mt   = r & 1;   r >>= 1;
        int ks   = r & 7;   r >>= 3;
        int tap  = r;                     // 0..8
        int m = mt * 16 + (lane & 15);
        int c = ks * 32 + (lane >> 4) * 8 + j;
        float v = (m < 18) ? ow[(m * 256 + c) * 9 + tap] : 0.f;
        aOW[idx] = __float2bfloat16(v);
    }
    if (idx < 147456) {
        int j    = idx & 7;
        int r    = idx >> 3;
        int lane = r & 63;  r >>= 6;
        int ct   = r & 1;   r >>= 1;
        int half = r & 1;   r >>= 1;
        int ks   = r & 1;   r >>= 1;
        int tap  = r % 9;
        int g    = r / 9;
        int c  = ks * 32 + (lane >> 4) * 8 + j;
        int co = half * 32 + ct * 16 + (lane & 15);
        float v = wt[(((g * CG_ + co) * CG_ + c) * 9) + tap];
        aW[idx] = __float2bfloat16(v);
    }
}

// ---------------------------------------------------------------------------
// transpose x (NCHW fp32) -> xtp (padded NHWC bf16, [b][98][98][256], halo=0).
// ---------------------------------------------------------------------------
__global__ __launch_bounds__(256) void transpose_kernel(
    const float* __restrict__ x, __hip_bfloat16* __restrict__ xtp)
{
    int blk = blockIdx.x;                 // 0..383 = b*96 + h
    int b = blk / H_, h = blk - b * H_;
    int t = threadIdx.x;
    __shared__ __align__(16) __hip_bfloat16 tile[96 * 264];
    const float* xb = x + (size_t)b * C_ * HW_ + h * W_;
    for (int r = 0; r < 96; ++r) {
        int e = r * 256 + t;              // 0..24575
        int c = e / 96, w = e - c * 96;
        tile[w * 264 + c] = __float2bfloat16(xb[c * HW_ + w]);
    }
    __syncthreads();
    __hip_bfloat16* ob = xtp + ((size_t)(b * PW_ + h + 1) * PW_ + 1) * C_;
#pragma unroll
    for (int i = 0; i < 12; ++i) {
        int sIdx = i * 256 + t;           // 0..3071
        int px = sIdx >> 5, seg = sIdx & 31;
        *(bf16x8*)(ob + px * 256 + seg * 8) =
            *(const bf16x8*)(&tile[px * 264 + seg * 8]);
    }
    bf16x8 z = {};
    if (t < 64) {                         // column halos of this row
        int side = t >> 5, i = t & 31;
        *(bf16x8*)(xtp + ((size_t)(b * PW_ + h + 1) * PW_ + side * 97) * C_ + i * 8) = z;
    }
    if (h == 0 || h == 95) {              // top/bottom halo rows
        int row = (h == 0) ? 0 : 97;
        __hip_bfloat16* rb = xtp + (size_t)(b * PW_ + row) * PROW_;
#pragma unroll
        for (int i = 0; i < 13; ++i) {
            int idx = i * 256 + t;
            if (idx < 3136) *(bf16x8*)(rb + idx * 8) = z;
        }
    }
}

// ---------------------------------------------------------------------------
// offset conv via MFMA, K-split 2 halves + A staged in LDS (double-buffered,
// 1 barrier/tap). Kills the 6x A re-read through L1 (each (tap,kh) A-slice
// was fetched by all 6 w-tile waves): global bytes/block 1.3MB -> 0.58MB.
// 384 blocks x 768 thr = 12 waves = 6 w-tiles(16) x 2 k-halves(128c).
// ---------------------------------------------------------------------------
__global__ __launch_bounds__(768) void offset_conv_kernel(
    const __hip_bfloat16* __restrict__ xtp, const __hip_bfloat16* __restrict__ aOW,
    const float* __restrict__ bias, __hip_bfloat16* __restrict__ off2)
{
    int blk = blockIdx.x;                 // 0..383
    int xcd = blk & 7;
    int s   = blk >> 3;                   // 0..47
    int bh  = xcd * 48 + s;               // XCD-chunked: neighbors share rows
    int b   = bh / H_, h = bh % H_;
    int t = threadIdx.x, lane = t & 63;
    int ww = __builtin_amdgcn_readfirstlane(t >> 6);  // 0..11
    int nt = ww % 6;                      // w tile
    int kh = ww / 6;                      // k half
    int w0 = nt * 16;
    int ml = lane & 15, kq = lane >> 4;

    __shared__ __align__(16) __hip_bfloat16 aS[2][8192];   // per-tap A slice
    __shared__ __align__(16) f32x4 red[6 * 64 * 2];

    auto stage = [&](int tap, int p) {
        const bf16x8* src = (const bf16x8*)(aOW + tap * 8192);
        bf16x8* dst = (bf16x8*)aS[p];
        for (int i = t; i < 1024; i += 768) dst[i] = src[i];
    };

    f32x4 acc0 = {}, acc1 = {};
    const __hip_bfloat16* xb = xtp + (size_t)b * (PW_ * PROW_);

    stage(0, 0);
    __syncthreads();
    for (int tap = 0; tap < 9; ++tap) {
        if (tap < 8) stage(tap + 1, (tap + 1) & 1);   // loads issue early
        int ky = tap / 3, kx = tap - ky * 3;
        const __hip_bfloat16* brow =
            xb + ((h + ky) * PW_ + (w0 + ml + kx)) * C_ + kh * 128 + kq * 8;
        const __hip_bfloat16* arow = aS[tap & 1] + kh * 4096 + lane * 8;
#pragma unroll
        for (int ks = 0; ks < 4; ++ks) {
            bf16x8 bf = *(const bf16x8*)(brow + ks * 32);
            bf16x8 a0 = *(const bf16x8*)(arow + ks * 1024);
            bf16x8 a1 = *(const bf16x8*)(arow + ks * 1024 + 512);
            acc0 = __builtin_amdgcn_mfma_f32_16x16x32_bf16(a0, bf, acc0, 0, 0, 0);
            acc1 = __builtin_amdgcn_mfma_f32_16x16x32_bf16(a1, bf, acc1, 0, 0, 0);
        }
        __syncthreads();
    }

    // cross-half reduction in LDS
    if (kh == 1) {
        red[(nt * 64 + lane) * 2 + 0] = acc0;
        red[(nt * 64 + lane) * 2 + 1] = acc1;
    }
    __syncthreads();
    if (kh == 0) {
        acc0 += red[(nt * 64 + lane) * 2 + 0];
        acc1 += red[(nt * 64 + lane) * 2 + 1];
        // C/D: col=lane&15 -> w, row=kq*4+r -> out channel j
        int w = w0 + ml;
#pragma unroll
        for (int r = 0; r < 4; ++r) {
            int j0 = kq * 4 + r;
            off2[((size_t)(b * 9 + (j0 >> 1)) * HW_ + h * W_ + w) * 2 + (j0 & 1)] =
                __float2bfloat16(acc0[r] + bias[j0]);
            int j1 = 16 + kq * 4 + r;
            if (j1 < 18)
                off2[((size_t)(b * 9 + (j1 >> 1)) * HW_ + h * W_ + w) * 2 + (j1 & 1)] =
                    __float2bfloat16(acc1[r] + bias[j1]);
        }
    }
}

// ---------------------------------------------------------------------------
// deform conv via MFMA: r5 structure (double-buffered LDS B-tile, 1 barrier
// per tap, sample(k+1) overlaps mmtap(k); 27.6KB LDS -> 5 blocks/CU) with
// LEAN setup: halo-clamp trick — valid samples' 4 corners always lie inside
// the padded image, so no clamps / per-corner masks / variable steps; invalid
// samples cndmask base->halo + wy->0. (r7's LDS table dedup reverted: it
// halved occupancy, costing more than the VALU it saved.)
// ---------------------------------------------------------------------------
__global__ __launch_bounds__(384, 4) void deform_kernel(
    const __hip_bfloat16* __restrict__ xtp, const __hip_bfloat16* __restrict__ off2,
    const __hip_bfloat16* __restrict__ aW, float* __restrict__ out)
{
    int blk = blockIdx.x;                 // 0..1535
    int xcd = blk & 7;
    int s   = blk >> 3;                   // 0..191
    int bg  = xcd * 2 + (s / H_);         // 0..15
    int h   = s % H_;
    int g   = bg & 3;
    int b   = bg >> 2;
    int t    = threadIdx.x;
    int lane = t & 63;
    int wave = __builtin_amdgcn_readfirstlane(t >> 6);  // 0..5
    int half   = wave & 1;                // co half (32)
    int wthird = wave >> 1;               // w third (32)

    __shared__ __align__(16) __hip_bfloat16 sS[2][96 * 72]; // [w][64c+pad]

    // interior origin: padded (1,1) == image (0,0)
    const __hip_bfloat16* xb =
        xtp + ((size_t)b * (PW_ * PW_) + PW_ + 1) * C_ + g * CG_;
    const __hip_bfloat162* offp =
        (const __hip_bfloat162*)off2 + (size_t)(b * 9) * HW_ + h * W_;
    const __hip_bfloat16* aWg = aW + (g * 9) * 4096;

    int tw8 = t >> 3;                     // 0..47
    int j8  = (t & 7) * 8;                // c offset within group

    f32x4 acc[2][2] = {};                 // [ct co16][wt w16]

    auto sample = [&](int k, int p) {
        int ky = k / 3, kx = k - ky * 3;
#pragma unroll
        for (int it = 0; it < 2; ++it) {
            int w  = it * 48 + tw8;
            __hip_bfloat162 pr = offp[k * HW_ + w];
            float py = (float)(h + ky - 1) + __bfloat162float(pr.x);
            float px = (float)(w + kx - 1) + __bfloat162float(pr.y);
            bool valid = (py > -1.f) && (py < (float)H_) &&
                         (px > -1.f) && (px < (float)W_);
            float y0f = floorf(py), x0f = floorf(px);
            float ly = py - y0f, lx = px - x0f;
            int y0 = (int)y0f, x0 = (int)x0f;
            // valid => y0,x0 in [-1,95]; all 4 corners inside padded image.
            // invalid => base -> padded (0,0) halo corner, weights zeroed.
            int base = valid ? (y0 * PW_ + x0) * C_ : -(PW_ + 1) * C_;
            float wy1 = valid ? ly : 0.f;
            float wy0 = valid ? (1.f - ly) : 0.f;
            float mx0 = 1.f - lx;
            float bw00 = wy0 * mx0, bw01 = wy0 * lx;
            float bw10 = wy1 * mx0, bw11 = wy1 * lx;
            const __hip_bfloat16* p0 = xb + base + j8;
            bf16x8 c00 = *(const bf16x8*)(p0);
            bf16x8 c01 = *(const bf16x8*)(p0 + C_);
            bf16x8 c10 = *(const bf16x8*)(p0 + PROW_);
            bf16x8 c11 = *(const bf16x8*)(p0 + PROW_ + C_);
            bf16x8 r;
#pragma unroll
            for (int e = 0; e < 8; ++e) {
                float v = bw00 * (float)c00[e] + bw01 * (float)c01[e]
                        + bw10 * (float)c10[e] + bw11 * (float)c11[e];
                r[e] = (__bf16)v;
            }
            *(bf16x8*)(&sS[p][w * 72 + j8]) = r;
        }
    };

    auto mmtap = [&](int k, int p) {
        bf16x8 afrag[2][2];               // [ks][ct]
        const __hip_bfloat16* at = aWg + k * 4096 + half * 1024 + lane * 8;
#pragma unroll
        for (int ks = 0; ks < 2; ++ks)
#pragma unroll
            for (int ct = 0; ct < 2; ++ct)
                afrag[ks][ct] = *(const bf16x8*)(at + ks * 2048 + ct * 512);
#pragma unroll
        for (int ks = 0; ks < 2; ++ks) {
#pragma unroll
            for (int wt = 0; wt < 2; ++wt) {
                int wrow = wthird * 32 + wt * 16 + (lane & 15);
                bf16x8 bfrag = *(const bf16x8*)(
                    &sS[p][wrow * 72 + ks * 32 + (lane >> 4) * 8]);
                acc[0][wt] = __builtin_amdgcn_mfma_f32_16x16x32_bf16(
                                 afrag[ks][0], bfrag, acc[0][wt], 0, 0, 0);
                acc[1][wt] = __builtin_amdgcn_mfma_f32_16x16x32_bf16(
                                 afrag[ks][1], bfrag, acc[1][wt], 0, 0, 0);
            }
        }
    };

    sample(0, 0);
    __syncthreads();
    for (int k = 0; k < K_; ++k) {
        if (k < K_ - 1) sample(k + 1, (k + 1) & 1);  // loads issue early
        mmtap(k, k & 1);
        __syncthreads();
    }

    // epilogue: C/D layout col=lane&15 (w), row=(lane>>4)*4+reg (co)
    float* ob = out + ((b * C_ + g * CG_ + half * 32) * HW_) + h * W_ + wthird * 32;
    int rbase = (lane >> 4) * 4;
    int ncol  = lane & 15;
#pragma unroll
    for (int ct = 0; ct < 2; ++ct)
#pragma unroll
        for (int wt = 0; wt < 2; ++wt)
#pragma unroll
            for (int r = 0; r < 4; ++r)
                __builtin_nontemporal_store(
                    acc[ct][wt][r],
                    ob + (ct * 16 + rbase + r) * HW_ + wt * 16 + ncol);
}

// ---------------------------------------------------------------------------
extern "C" void kernel_launch(void* const* d_in, const int* in_sizes, int n_in,
                              void* d_out, int out_size, void* d_ws, size_t ws_size,
                              hipStream_t stream) {
    const float* x    = (const float*)d_in[0];
    const float* ow   = (const float*)d_in[1];   // offset_w (18,256,3,3)
    const float* obi  = (const float*)d_in[2];   // offset_b (18,)
    const float* wt   = (const float*)d_in[3];   // weight   (256,64,3,3)

    // ws: xtp bf16 padded (19.67MB) | off2 bf16 (1.33MB) | aW (0.29MB) | aOW (0.15MB)
    __hip_bfloat16* xtp  = (__hip_bfloat16*)d_ws;
    __hip_bfloat16* off2 = xtp + (size_t)B_ * PW_ * PW_ * C_;
    __hip_bfloat16* aW   = off2 + (size_t)B_ * 9 * HW_ * 2;
    __hip_bfloat16* aOW  = aW + 147456;

    prep_kernel<<<576, 256, 0, stream>>>(ow, wt, aOW, aW);
    transpose_kernel<<<B_ * H_, 256, 0, stream>>>(x, xtp);
    offset_conv_kernel<<<B_ * H_, 768, 0, stream>>>(xtp, aOW, obi, off2);
    deform_kernel<<<B_ * G_ * H_, 384, 0, stream>>>(xtp, off2, aW, (float*)d_out);
}